// Round 14
// baseline (1305.614 us; speedup 1.0000x reference)
//
#include <hip/hip_runtime.h>
#include <hip/hip_fp16.h>

#define N_NODES 100000
#define E_EDGES 1600000
#define IN_C    128
#define HID_C   64
#define OUT_C   64
#define ROWS    32
#define NBUCK   391         // ceil(100000/256) node buckets
#define BSHIFT  8
#define BNODES  256
#define CAP     5120        // bucket capacity (mean 4096, +16 sigma)
#define CHUNK   4096
#define NB_BINCH 391        // ceil(E/CHUNK) bin chunks
#define NB_TR   112
#define IDXCAP  1632
#define IDXMAX  1568

typedef _Float16 f16x8 __attribute__((ext_vector_type(8)));
typedef float    f32x4 __attribute__((ext_vector_type(4)));
#define MFMA16(a, b, c) __builtin_amdgcn_mfma_f32_16x16x32_f16(a, b, c, 0, 0, 0)

// =============== K1: edge binning (blocks 0..390) + weight transpose (391..502) ===============
struct BinS {
    int hist[NBUCK]; int resbase[NBUCK]; int cur[NBUCK];
    unsigned pk[CHUNK]; unsigned short bk[CHUNK];
};

__global__ __launch_bounds__(256) void k1_bin_tr(const int* __restrict__ ei,
                                                 int* __restrict__ bucket_cursor,
                                                 unsigned* __restrict__ gbuck,
                                                 const float* __restrict__ Wi,
                                                 const float* __restrict__ Wsf,
                                                 const float* __restrict__ Waf,
                                                 const float* __restrict__ Wo,
                                                 _Float16* __restrict__ wtr) {
    __shared__ BinS S;
    int tid = threadIdx.x;
    if (blockIdx.x < NB_BINCH) {
        for (int i = tid; i < NBUCK; i += 256) S.hist[i] = 0;
        __syncthreads();
        int base = blockIdx.x * CHUNK;
        for (int i = tid; i < CHUNK; i += 256) {
            int e = base + i;
            if (e < E_EDGES) {
                int dst = ei[e];
                int src = ei[E_EDGES + e];
                int b = dst >> BSHIFT;
                S.pk[i] = ((unsigned)(dst & (BNODES - 1)) << 17) | (unsigned)src;
                S.bk[i] = (unsigned short)b;
                atomicAdd(&S.hist[b], 1);
            } else S.bk[i] = 0xFFFF;
        }
        __syncthreads();
        for (int i = tid; i < NBUCK; i += 256) {
            S.resbase[i] = atomicAdd(&bucket_cursor[i], S.hist[i]);
            S.cur[i] = 0;
        }
        __syncthreads();
        for (int i = tid; i < CHUNK; i += 256) {
            if (S.bk[i] != 0xFFFF) {
                int b = S.bk[i];
                int slot = S.resbase[b] + atomicAdd(&S.cur[b], 1);
                if (slot < CAP) gbuck[(size_t)b * CAP + slot] = S.pk[i];
            }
        }
    } else {
        // weight transpose: [0,8704) init 64x136 | [8704,17408) L0 | [17408,26112) L1 | [26112,30720) out 64x72
        int t = (blockIdx.x - NB_BINCH) * 256 + tid;
        if (t < 8192) {
            int k = t >> 6, col = t & 63;
            wtr[col * 136 + k] = (_Float16)Wi[t];
        } else if (t < 24576) {
            int u = t - 8192; int l = u >> 13; int v = u & 8191;
            int k = v >> 6, col = v & 63;
            float w = (k < 64) ? Waf[l * 4096 + k * 64 + col] : Wsf[l * 4096 + (k - 64) * 64 + col];
            wtr[8704 + l * 8704 + col * 136 + k] = (_Float16)w;
        } else if (t < 28672) {
            int u = t - 24576; int k = u >> 6, col = u & 63;
            wtr[26112 + col * 72 + k] = (_Float16)Wo[u];
        }
    }
}

// =============== K2: bucket CSR build (blocks 0..390) + init GEMM (391..3515) ===============
struct InitS { _Float16 sA[ROWS][IN_C + 8]; _Float16 sBt[HID_C][IN_C + 8]; };
struct BuildS { int lcnt[BNODES]; int lpos[BNODES]; int lcur[BNODES]; int s[2][512]; };
union K2S { InitS ini; BuildS bld; };

// MFMA tile with LDS-staged B
template<int K>
__device__ __forceinline__ void mfma_tile(const _Float16* sA, const _Float16* sBt,
                                          int lane, int wave, f32x4 acc[2]) {
    const int LDA = K + 8;
    int r0 = (wave >> 1) * 16;
    int wc = wave & 1;
    int m = lane & 15, kg = lane >> 4;
    acc[0] = (f32x4){0.f, 0.f, 0.f, 0.f};
    acc[1] = (f32x4){0.f, 0.f, 0.f, 0.f};
    #pragma unroll
    for (int ks = 0; ks < K / 32; ++ks) {
        f16x8 a = *(const f16x8*)&sA[(r0 + m) * LDA + 32 * ks + 8 * kg];
        #pragma unroll
        for (int nt = 0; nt < 2; ++nt) {
            f16x8 b = *(const f16x8*)&sBt[(wc * 32 + nt * 16 + m) * LDA + 32 * ks + 8 * kg];
            acc[nt] = MFMA16(a, b, acc[nt]);
        }
    }
}

// MFMA tile with register-resident B fragments
template<int NKS>
__device__ __forceinline__ void mfma_regB(const _Float16* aBase, int lda, int m,
                                          int kg, const f16x8* bf0, const f16x8* bf1,
                                          f32x4 acc[2]) {
    #pragma unroll
    for (int ks = 0; ks < NKS; ++ks) {
        f16x8 a = *(const f16x8*)&aBase[m * lda + 32 * ks + 8 * kg];
        acc[0] = MFMA16(a, bf0[ks], acc[0]);
        acc[1] = MFMA16(a, bf1[ks], acc[1]);
    }
}

__global__ __launch_bounds__(256) void k2_build_init(const unsigned* __restrict__ gbuck,
                                                     const int* __restrict__ bucket_cursor,
                                                     unsigned* __restrict__ csr,
                                                     int2* __restrict__ rc,
                                                     const float* __restrict__ x,
                                                     const float4* __restrict__ wtrI,
                                                     __half* __restrict__ h) {
    __shared__ K2S U;
    int t = threadIdx.x;
    if (blockIdx.x < NBUCK) {
        BuildS& S = U.bld;
        int b = blockIdx.x;
        int v0 = (t < NBUCK) ? min(bucket_cursor[t], CAP) : 0;
        int v1 = (t + 256 < NBUCK) ? min(bucket_cursor[t + 256], CAP) : 0;
        S.s[0][t] = v0; S.s[0][t + 256] = v1;
        S.lcnt[t] = 0; S.lcur[t] = 0;
        __syncthreads();
        int p = 0;
        for (int off = 1; off < 512; off <<= 1) {
            int a0 = S.s[p][t]       + ((t >= off)       ? S.s[p][t - off] : 0);
            int a1 = S.s[p][t + 256] + ((t + 256 >= off) ? S.s[p][t + 256 - off] : 0);
            S.s[p ^ 1][t] = a0; S.s[p ^ 1][t + 256] = a1;
            __syncthreads();
            p ^= 1;
        }
        int bb = (b == 0) ? 0 : S.s[p][b - 1];
        int ec = min(bucket_cursor[b], CAP);
        int gnode = b * BNODES;
        int nn = min(BNODES, N_NODES - gnode);
        const unsigned* mybuck = gbuck + (size_t)b * CAP;
        __syncthreads();
        for (int i = t; i < ec; i += 256) atomicAdd(&S.lcnt[mybuck[i] >> 17], 1);
        __syncthreads();
        int c = S.lcnt[t];
        S.s[0][t] = c;
        __syncthreads();
        int q = 0;
        for (int off = 1; off < 256; off <<= 1) {
            int a0 = S.s[q][t] + ((t >= off) ? S.s[q][t - off] : 0);
            S.s[q ^ 1][t] = a0;
            __syncthreads();
            q ^= 1;
        }
        int ex = S.s[q][t] - c;
        S.lpos[t] = ex;
        if (t < nn) rc[gnode + t] = make_int2(bb + ex, c);
        __syncthreads();
        for (int i = t; i < ec; i += 256) {
            unsigned pkt = mybuck[i];
            int dl = pkt >> 17;
            int slot = S.lpos[dl] + atomicAdd(&S.lcur[dl], 1);
            // store packed: dst-local-to-32-row-block (5b) | src (17b)
            csr[bb + slot] = ((unsigned)(dl & 31) << 17) | (pkt & 0x1FFFFu);
        }
    } else {
        InitS& S = U.ini;
        int row0 = (blockIdx.x - NBUCK) * ROWS;
        float4* sB4 = (float4*)&S.sBt[0][0];
        for (int i = t; i < 1088; i += 256) sB4[i] = wtrI[i];
        const float4* x4 = (const float4*)x;
        for (int i = t; i < ROWS * 32; i += 256) {
            int r = i >> 5, qq = i & 31;
            float4 f = x4[(size_t)(row0 + r) * 32 + qq];
            __half2 ha = __floats2half2_rn(f.x, f.y), hb = __floats2half2_rn(f.z, f.w);
            uint2 u; u.x = *(unsigned*)&ha; u.y = *(unsigned*)&hb;
            *(uint2*)&S.sA[r][qq * 4] = u;
        }
        __syncthreads();
        int lane = t & 63, wave = t >> 6;
        f32x4 acc[2];
        mfma_tile<IN_C>(&S.sA[0][0], &S.sBt[0][0], lane, wave, acc);
        int m = lane & 15, rg = lane >> 4;
        int r0 = (wave >> 1) * 16, wc = wave & 1;
        #pragma unroll
        for (int nt = 0; nt < 2; ++nt) {
            int col = wc * 32 + nt * 16 + m;
            #pragma unroll
            for (int i = 0; i < 4; ++i) {
                int row = row0 + r0 + rg * 4 + i;
                h[(size_t)row * HID_C + col] = __float2half(acc[nt][i]);
            }
        }
    }
}

// =============== fused: edge-parallel LDS-atomic (f32) gather + reg-B MFMA + ReLU [+ out GEMM] ===============
template<bool FINAL>
__global__ __launch_bounds__(256, 6) void fused_layer(const __half* __restrict__ h,
                                                      const int2* __restrict__ rc,
                                                      const unsigned* __restrict__ csr,
                                                      const _Float16* __restrict__ wB,
                                                      const float* __restrict__ bias,
                                                      __half* __restrict__ hout,
                                                      const _Float16* __restrict__ wO,
                                                      float* __restrict__ out) {
    __shared__ _Float16 sA[ROWS][136];     // [row][k]: k<64 agg (from sAgg), k>=64 self
    __shared__ float sAgg[ROWS][HID_C];    // fp32 atomic accumulator, 8 KB
    __shared__ unsigned sIdx[IDXCAP];      // block's contiguous csr span (packed rl|src)
    __shared__ float sInv[ROWS];
    int tid = threadIdx.x;
    int wave = tid >> 6, lane = tid & 63;
    int m = lane & 15, kg = lane >> 4, wc = wave & 1;
    int row0 = blockIdx.x * ROWS;
    const uint2* h2u = (const uint2*)h;    // row = 16 uint2
    const uint4* h4 = (const uint4*)h;

    // zero agg + stage self rows + per-row inv-degree
    {
        int r = tid >> 3, qq = tid & 7;
        float4 z; z.x = 0.f; z.y = 0.f; z.z = 0.f; z.w = 0.f;
        *(float4*)&sAgg[r][qq * 8]     = z;
        *(float4*)&sAgg[r][qq * 8 + 4] = z;
        *(uint4*)&sA[r][64 + qq * 8] = h4[(size_t)(row0 + r) * 8 + qq];
    }
    if (tid < 32) {
        int2 v = rc[row0 + tid];
        sInv[tid] = 1.f / fmaxf((float)v.y, 1.f);
    }
    int2 rcF = rc[row0];
    int2 rcL = rc[row0 + 31];
    int e0 = __builtin_amdgcn_readfirstlane(rcF.x);
    int e1 = __builtin_amdgcn_readfirstlane(rcL.x) + __builtin_amdgcn_readfirstlane(rcL.y);
    int L = min(e1 - e0, IDXMAX);
    for (int i = tid; i < L; i += 256) sIdx[i] = csr[e0 + i];
    if (tid < 64) sIdx[min(L + tid, IDXCAP - 1)] = 0u;     // pad (rl=0, src=0)
    __syncthreads();

    // edge-parallel gather: 16 teams x 16 lanes; team j handles edges j*8+u per 128-edge stripe.
    // Tail is branch-free: clamped index + zeroed value -> atomic add of 0 to row 0.
    int team = tid >> 4;       // 0..15
    int cl   = tid & 15;       // channel chunk: channels [4*cl, 4*cl+4)
    for (int base = 0; base < L; base += 128) {
        #pragma unroll
        for (int u = 0; u < 8; ++u) {
            int e = base + team * 8 + u;
            unsigned pk = sIdx[min(e, IDXCAP - 1)];
            bool ok = e < L;
            int src = (int)(pk & 0x1FFFFu);
            int rl  = (int)(pk >> 17) & 31;
            uint2 v = h2u[(size_t)src * 16 + cl];
            unsigned vx = ok ? v.x : 0u, vy = ok ? v.y : 0u;
            float2 f01 = __half22float2(*(__half2*)&vx);
            float2 f23 = __half22float2(*(__half2*)&vy);
            atomicAdd(&sAgg[rl][4 * cl],     f01.x);
            atomicAdd(&sAgg[rl][4 * cl + 1], f01.y);
            atomicAdd(&sAgg[rl][4 * cl + 2], f23.x);
            atomicAdd(&sAgg[rl][4 * cl + 3], f23.y);
        }
    }
    __syncthreads();

    // scale agg by 1/deg, convert to fp16 into the MFMA A-tile
    {
        int r = tid >> 3, qq = tid & 7;
        float inv = sInv[r];
        float4 a0 = *(float4*)&sAgg[r][qq * 8];
        float4 a1 = *(float4*)&sAgg[r][qq * 8 + 4];
        __half2 q0 = __floats2half2_rn(a0.x * inv, a0.y * inv);
        __half2 q1 = __floats2half2_rn(a0.z * inv, a0.w * inv);
        __half2 q2 = __floats2half2_rn(a1.x * inv, a1.y * inv);
        __half2 q3 = __floats2half2_rn(a1.z * inv, a1.w * inv);
        uint4 o;
        o.x = *(unsigned*)&q0; o.y = *(unsigned*)&q1;
        o.z = *(unsigned*)&q2; o.w = *(unsigned*)&q3;
        *(uint4*)&sA[r][qq * 8] = o;
    }

    // B fragments -> registers (wtr is L2-hot)
    f16x8 bf0[4], bf1[4];
    #pragma unroll
    for (int ks = 0; ks < 4; ++ks) {
        bf0[ks] = *(const f16x8*)&wB[(wc * 32 + m) * 136 + 32 * ks + 8 * kg];
        bf1[ks] = *(const f16x8*)&wB[(wc * 32 + 16 + m) * 136 + 32 * ks + 8 * kg];
    }
    __syncthreads();

    f32x4 acc[2];
    acc[0] = (f32x4){0.f, 0.f, 0.f, 0.f};
    acc[1] = (f32x4){0.f, 0.f, 0.f, 0.f};
    int r0 = (wave >> 1) * 16;
    mfma_regB<4>(&sA[r0][0], 136, m, kg, bf0, bf1, acc);
    int rg = lane >> 4;
    if (!FINAL) {
        #pragma unroll
        for (int nt = 0; nt < 2; ++nt) {
            int col = wc * 32 + nt * 16 + m;
            float bv = bias[col];
            f32x4 a = (nt == 0) ? acc[0] : acc[1];
            #pragma unroll
            for (int i = 0; i < 4; ++i) {
                int row = row0 + r0 + rg * 4 + i;
                hout[(size_t)row * HID_C + col] = __float2half(fmaxf(a[i] + bv, 0.f));
            }
        }
    } else {
        __syncthreads();     // all MFMA1 LDS reads complete
        _Float16* sA72 = &sA[0][0];
        #pragma unroll
        for (int nt = 0; nt < 2; ++nt) {
            int col = wc * 32 + nt * 16 + m;
            float bv = bias[col];
            f32x4 a = (nt == 0) ? acc[0] : acc[1];
            #pragma unroll
            for (int i = 0; i < 4; ++i) {
                int rl = r0 + rg * 4 + i;
                sA72[rl * 72 + col] = (_Float16)fmaxf(a[i] + bv, 0.f);
            }
        }
        f16x8 of0[2], of1[2];
        #pragma unroll
        for (int ks = 0; ks < 2; ++ks) {
            of0[ks] = *(const f16x8*)&wO[(wc * 32 + m) * 72 + 32 * ks + 8 * kg];
            of1[ks] = *(const f16x8*)&wO[(wc * 32 + 16 + m) * 72 + 32 * ks + 8 * kg];
        }
        __syncthreads();
        f32x4 acc2[2];
        acc2[0] = (f32x4){0.f, 0.f, 0.f, 0.f};
        acc2[1] = (f32x4){0.f, 0.f, 0.f, 0.f};
        mfma_regB<2>(&sA72[r0 * 72], 72, m, kg, of0, of1, acc2);
        #pragma unroll
        for (int nt = 0; nt < 2; ++nt) {
            int col = wc * 32 + nt * 16 + m;
            f32x4 a = (nt == 0) ? acc2[0] : acc2[1];
            #pragma unroll
            for (int i = 0; i < 4; ++i) {
                int row = row0 + r0 + rg * 4 + i;
                out[(size_t)row * OUT_C + col] = a[i];
            }
        }
    }
}

extern "C" void kernel_launch(void* const* d_in, const int* in_sizes, int n_in,
                              void* d_out, int out_size, void* d_ws, size_t ws_size,
                              hipStream_t stream) {
    const float* x      = (const float*)d_in[0];
    const int*   ei     = (const int*)  d_in[1];
    const float* W_init = (const float*)d_in[2];
    const float* W_self = (const float*)d_in[3];
    const float* W_agg  = (const float*)d_in[4];
    const float* b      = (const float*)d_in[5];
    const float* W_out  = (const float*)d_in[6];
    float* out = (float*)d_out;

    char* ws = (char*)d_ws;
    const size_t KB = 1 << 10;
    int*      bucket_cursor = (int*)(ws + 0);                 // 1.6 KB
    int2*     rc            = (int2*)(ws + 4 * KB);           // 800 KB
    unsigned* csr           = (unsigned*)(ws + 1024 * KB);    // 6.4 MB
    _Float16* wtr           = (_Float16*)(ws + 7424 * KB);    // 60 KB
    unsigned* gbuck         = (unsigned*)(ws + 8192 * KB);    // 7.82 MB
    __half*   hA            = (__half*)(ws + 18432 * KB);     // 12.8 MB
    __half*   hB            = (__half*)(ws + 32768 * KB);     // 12.8 MB

    const float4*   wtrI  = (const float4*)(wtr);
    const _Float16* wtrL0 = wtr + 8704;
    const _Float16* wtrL1 = wtr + 17408;
    const _Float16* wtrO  = wtr + 26112;

    (void)hipMemsetAsync(bucket_cursor, 0, NBUCK * sizeof(int), stream);
    k1_bin_tr<<<NB_BINCH + NB_TR, 256, 0, stream>>>(ei, bucket_cursor, gbuck,
                                                    W_init, W_self, W_agg, W_out, wtr);
    k2_build_init<<<NBUCK + N_NODES / ROWS, 256, 0, stream>>>(gbuck, bucket_cursor, csr, rc,
                                                              x, wtrI, hA);
    const int GB = N_NODES / ROWS;   // 3125
    fused_layer<false><<<GB, 256, 0, stream>>>(hA, rc, csr, wtrL0, b + 0 * HID_C, hB,
                                               wtrO, out);
    fused_layer<true><<<GB, 256, 0, stream>>>(hB, rc, csr, wtrL1, b + 1 * HID_C, hA,
                                              wtrO, out);
}

// Round 15
// 135.888 us; speedup vs baseline: 9.6080x; 9.6080x over previous
//
#include <hip/hip_runtime.h>
#include <hip/hip_fp16.h>

#define N_NODES 100000
#define E_EDGES 1600000
#define IN_C    128
#define HID_C   64
#define OUT_C   64
#define ROWS    32
#define NBUCK   391         // ceil(100000/256) node buckets
#define BSHIFT  8
#define BNODES  256
#define CAP     5120        // bucket capacity (mean 4096, +16 sigma)
#define CHUNK   4096
#define NB_BINCH 391        // ceil(E/CHUNK) bin chunks
#define NB_TR   112
#define IDXCAP  1632
#define IDXMAX  1568

typedef _Float16 f16x8 __attribute__((ext_vector_type(8)));
typedef float    f32x4 __attribute__((ext_vector_type(4)));
#define MFMA16(a, b, c) __builtin_amdgcn_mfma_f32_16x16x32_f16(a, b, c, 0, 0, 0)

// =============== K1: edge binning (blocks 0..390) + weight transpose (391..502) ===============
struct BinS {
    int hist[NBUCK]; int resbase[NBUCK]; int cur[NBUCK];
    unsigned pk[CHUNK]; unsigned short bk[CHUNK];
};

__global__ __launch_bounds__(256) void k1_bin_tr(const int* __restrict__ ei,
                                                 int* __restrict__ bucket_cursor,
                                                 unsigned* __restrict__ gbuck,
                                                 const float* __restrict__ Wi,
                                                 const float* __restrict__ Wsf,
                                                 const float* __restrict__ Waf,
                                                 const float* __restrict__ Wo,
                                                 _Float16* __restrict__ wtr) {
    __shared__ BinS S;
    int tid = threadIdx.x;
    if (blockIdx.x < NB_BINCH) {
        for (int i = tid; i < NBUCK; i += 256) S.hist[i] = 0;
        __syncthreads();
        int base = blockIdx.x * CHUNK;
        for (int i = tid; i < CHUNK; i += 256) {
            int e = base + i;
            if (e < E_EDGES) {
                int dst = ei[e];
                int src = ei[E_EDGES + e];
                int b = dst >> BSHIFT;
                S.pk[i] = ((unsigned)(dst & (BNODES - 1)) << 17) | (unsigned)src;
                S.bk[i] = (unsigned short)b;
                atomicAdd(&S.hist[b], 1);
            } else S.bk[i] = 0xFFFF;
        }
        __syncthreads();
        for (int i = tid; i < NBUCK; i += 256) {
            S.resbase[i] = atomicAdd(&bucket_cursor[i], S.hist[i]);
            S.cur[i] = 0;
        }
        __syncthreads();
        for (int i = tid; i < CHUNK; i += 256) {
            if (S.bk[i] != 0xFFFF) {
                int b = S.bk[i];
                int slot = S.resbase[b] + atomicAdd(&S.cur[b], 1);
                if (slot < CAP) gbuck[(size_t)b * CAP + slot] = S.pk[i];
            }
        }
    } else {
        // weight transpose: [0,8704) init 64x136 | [8704,17408) L0 | [17408,26112) L1 | [26112,30720) out 64x72
        int t = (blockIdx.x - NB_BINCH) * 256 + tid;
        if (t < 8192) {
            int k = t >> 6, col = t & 63;
            wtr[col * 136 + k] = (_Float16)Wi[t];
        } else if (t < 24576) {
            int u = t - 8192; int l = u >> 13; int v = u & 8191;
            int k = v >> 6, col = v & 63;
            float w = (k < 64) ? Waf[l * 4096 + k * 64 + col] : Wsf[l * 4096 + (k - 64) * 64 + col];
            wtr[8704 + l * 8704 + col * 136 + k] = (_Float16)w;
        } else if (t < 28672) {
            int u = t - 24576; int k = u >> 6, col = u & 63;
            wtr[26112 + col * 72 + k] = (_Float16)Wo[u];
        }
    }
}

// =============== K2: bucket CSR build (blocks 0..390) + init GEMM (391..3515) ===============
struct InitS { _Float16 sA[ROWS][IN_C + 8]; _Float16 sBt[HID_C][IN_C + 8]; };
struct BuildS { int lcnt[BNODES]; int lpos[BNODES]; int lcur[BNODES]; int s[2][512]; };
union K2S { InitS ini; BuildS bld; };

// MFMA tile with LDS-staged B
template<int K>
__device__ __forceinline__ void mfma_tile(const _Float16* sA, const _Float16* sBt,
                                          int lane, int wave, f32x4 acc[2]) {
    const int LDA = K + 8;
    int r0 = (wave >> 1) * 16;
    int wc = wave & 1;
    int m = lane & 15, kg = lane >> 4;
    acc[0] = (f32x4){0.f, 0.f, 0.f, 0.f};
    acc[1] = (f32x4){0.f, 0.f, 0.f, 0.f};
    #pragma unroll
    for (int ks = 0; ks < K / 32; ++ks) {
        f16x8 a = *(const f16x8*)&sA[(r0 + m) * LDA + 32 * ks + 8 * kg];
        #pragma unroll
        for (int nt = 0; nt < 2; ++nt) {
            f16x8 b = *(const f16x8*)&sBt[(wc * 32 + nt * 16 + m) * LDA + 32 * ks + 8 * kg];
            acc[nt] = MFMA16(a, b, acc[nt]);
        }
    }
}

// MFMA tile with register-resident B fragments
template<int NKS>
__device__ __forceinline__ void mfma_regB(const _Float16* aBase, int lda, int m,
                                          int kg, const f16x8* bf0, const f16x8* bf1,
                                          f32x4 acc[2]) {
    #pragma unroll
    for (int ks = 0; ks < NKS; ++ks) {
        f16x8 a = *(const f16x8*)&aBase[m * lda + 32 * ks + 8 * kg];
        acc[0] = MFMA16(a, bf0[ks], acc[0]);
        acc[1] = MFMA16(a, bf1[ks], acc[1]);
    }
}

__global__ __launch_bounds__(256) void k2_build_init(const unsigned* __restrict__ gbuck,
                                                     const int* __restrict__ bucket_cursor,
                                                     int* __restrict__ csr,
                                                     int2* __restrict__ rc,
                                                     const float* __restrict__ x,
                                                     const float4* __restrict__ wtrI,
                                                     __half* __restrict__ h) {
    __shared__ K2S U;
    int t = threadIdx.x;
    if (blockIdx.x < NBUCK) {
        BuildS& S = U.bld;
        int b = blockIdx.x;
        int v0 = (t < NBUCK) ? min(bucket_cursor[t], CAP) : 0;
        int v1 = (t + 256 < NBUCK) ? min(bucket_cursor[t + 256], CAP) : 0;
        S.s[0][t] = v0; S.s[0][t + 256] = v1;
        S.lcnt[t] = 0; S.lcur[t] = 0;
        __syncthreads();
        int p = 0;
        for (int off = 1; off < 512; off <<= 1) {
            int a0 = S.s[p][t]       + ((t >= off)       ? S.s[p][t - off] : 0);
            int a1 = S.s[p][t + 256] + ((t + 256 >= off) ? S.s[p][t + 256 - off] : 0);
            S.s[p ^ 1][t] = a0; S.s[p ^ 1][t + 256] = a1;
            __syncthreads();
            p ^= 1;
        }
        int bb = (b == 0) ? 0 : S.s[p][b - 1];
        int ec = min(bucket_cursor[b], CAP);
        int gnode = b * BNODES;
        int nn = min(BNODES, N_NODES - gnode);
        const unsigned* mybuck = gbuck + (size_t)b * CAP;
        __syncthreads();
        for (int i = t; i < ec; i += 256) atomicAdd(&S.lcnt[mybuck[i] >> 17], 1);
        __syncthreads();
        int c = S.lcnt[t];
        S.s[0][t] = c;
        __syncthreads();
        int q = 0;
        for (int off = 1; off < 256; off <<= 1) {
            int a0 = S.s[q][t] + ((t >= off) ? S.s[q][t - off] : 0);
            S.s[q ^ 1][t] = a0;
            __syncthreads();
            q ^= 1;
        }
        int ex = S.s[q][t] - c;
        S.lpos[t] = ex;
        if (t < nn) rc[gnode + t] = make_int2(bb + ex, c);
        __syncthreads();
        for (int i = t; i < ec; i += 256) {
            unsigned pkt = mybuck[i];
            int dl = pkt >> 17;
            int slot = S.lpos[dl] + atomicAdd(&S.lcur[dl], 1);
            csr[bb + slot] = (int)(pkt & 0x1FFFF);
        }
    } else {
        InitS& S = U.ini;
        int row0 = (blockIdx.x - NBUCK) * ROWS;
        float4* sB4 = (float4*)&S.sBt[0][0];
        for (int i = t; i < 1088; i += 256) sB4[i] = wtrI[i];
        const float4* x4 = (const float4*)x;
        for (int i = t; i < ROWS * 32; i += 256) {
            int r = i >> 5, qq = i & 31;
            float4 f = x4[(size_t)(row0 + r) * 32 + qq];
            __half2 ha = __floats2half2_rn(f.x, f.y), hb = __floats2half2_rn(f.z, f.w);
            uint2 u; u.x = *(unsigned*)&ha; u.y = *(unsigned*)&hb;
            *(uint2*)&S.sA[r][qq * 4] = u;
        }
        __syncthreads();
        int lane = t & 63, wave = t >> 6;
        f32x4 acc[2];
        mfma_tile<IN_C>(&S.sA[0][0], &S.sBt[0][0], lane, wave, acc);
        int m = lane & 15, rg = lane >> 4;
        int r0 = (wave >> 1) * 16, wc = wave & 1;
        #pragma unroll
        for (int nt = 0; nt < 2; ++nt) {
            int col = wc * 32 + nt * 16 + m;
            #pragma unroll
            for (int i = 0; i < 4; ++i) {
                int row = row0 + r0 + rg * 4 + i;
                h[(size_t)row * HID_C + col] = __float2half(acc[nt][i]);
            }
        }
    }
}

// =============== fused: two-phase deep-MLP gather + reg-B MFMA + ReLU [+ out GEMM] ===============
template<bool FINAL>
__global__ __launch_bounds__(256, 4) void fused_layer(const __half* __restrict__ h,
                                                      const int2* __restrict__ rc,
                                                      const int* __restrict__ csr,
                                                      const _Float16* __restrict__ wB,
                                                      const float* __restrict__ bias,
                                                      __half* __restrict__ hout,
                                                      const _Float16* __restrict__ wO,
                                                      float* __restrict__ out) {
    __shared__ _Float16 sA[ROWS][136];     // [row][k]: k<64 agg, k>=64 self
    __shared__ int sIdx[IDXCAP];           // block's contiguous csr span
    __shared__ int2 sRC[ROWS];
    int tid = threadIdx.x;
    int wave = tid >> 6, lane = tid & 63;
    int m = lane & 15, kg = lane >> 4, wc = wave & 1;
    int row0 = blockIdx.x * ROWS;
    const uint2* h2u = (const uint2*)h;    // row = 16 uint2
    const uint4* h4 = (const uint4*)h;

    if (tid < 32) sRC[tid] = rc[row0 + tid];
    int2 rcF = rc[row0];
    int2 rcL = rc[row0 + 31];
    int e0 = __builtin_amdgcn_readfirstlane(rcF.x);
    int e1 = __builtin_amdgcn_readfirstlane(rcL.x) + __builtin_amdgcn_readfirstlane(rcL.y);
    int Lc = min(e1 - e0, IDXMAX);
    for (int i = tid; i < Lc; i += 256) sIdx[i] = csr[e0 + i];
    if (tid < 64) sIdx[min(Lc + tid, IDXCAP - 1)] = 0;      // pad
    // stage self rows: 32 rows x 8 chunks = 256 threads, one uint4 each
    {
        int r = tid >> 3, qq = tid & 7;
        *(uint4*)&sA[r][64 + qq * 8] = h4[(size_t)(row0 + r) * 8 + qq];
    }
    __syncthreads();

    int g4 = lane >> 4;       // edge slot 0..3
    int c16 = lane & 15;      // channels [4*c16, 4*c16+4)
    int sl[8], dd[8];
    int dmax = 0;
    #pragma unroll
    for (int r = 0; r < 8; ++r) {
        int2 v = sRC[wave * 8 + r];
        sl[r] = min(__builtin_amdgcn_readfirstlane(v.x) - e0, IDXMAX);
        dd[r] = __builtin_amdgcn_readfirstlane(v.y);
        dmax = max(dmax, dd[r]);
    }
    const __half2 hzero = __floats2half2_rn(0.f, 0.f);
    __half2 p01[8], p23[8];
    #pragma unroll
    for (int r = 0; r < 8; ++r) { p01[r] = hzero; p23[r] = hzero; }

    // two-phase gather: per 8-edge step, issue ALL 16 loads (8 rows x 2 slots)
    // into a statically-indexed register buffer, THEN accumulate. dd/sl are
    // SGPR (readfirstlane) -> row-skip branches are scalar.
    for (int c8 = 0; c8 < dmax; c8 += 8) {
        uint2 v[8][2];
        // phase 1: loads only
        #pragma unroll
        for (int r = 0; r < 8; ++r) {
            if (c8 < dd[r]) {
                #pragma unroll
                for (int s = 0; s < 2; ++s) {
                    int ee = c8 + s * 4 + g4;
                    int src = sIdx[sl[r] + ee];
                    v[r][s] = h2u[(size_t)src * 16 + c16];
                }
            }
        }
        // phase 2: accumulates only
        #pragma unroll
        for (int r = 0; r < 8; ++r) {
            if (c8 < dd[r]) {
                #pragma unroll
                for (int s = 0; s < 2; ++s) {
                    int ee = c8 + s * 4 + g4;
                    bool ok = ee < dd[r];
                    unsigned vx = ok ? v[r][s].x : 0u, vy = ok ? v[r][s].y : 0u;
                    p01[r] += *(__half2*)&vx;
                    p23[r] += *(__half2*)&vy;
                }
            }
        }
    }

    // cross-slot reduce (packed fp16) + mean + write agg
    #pragma unroll
    for (int r = 0; r < 8; ++r) {
        unsigned u01 = *(unsigned*)&p01[r], u23 = *(unsigned*)&p23[r];
        unsigned o01 = (unsigned)__shfl_xor((int)u01, 16);
        unsigned o23 = (unsigned)__shfl_xor((int)u23, 16);
        p01[r] += *(__half2*)&o01; p23[r] += *(__half2*)&o23;
        u01 = *(unsigned*)&p01[r]; u23 = *(unsigned*)&p23[r];
        o01 = (unsigned)__shfl_xor((int)u01, 32);
        o23 = (unsigned)__shfl_xor((int)u23, 32);
        p01[r] += *(__half2*)&o01; p23[r] += *(__half2*)&o23;
        if (lane < 16) {
            __half2 hinv = __float2half2_rn(1.f / fmaxf((float)dd[r], 1.f));
            __half2 q01 = p01[r] * hinv, q23 = p23[r] * hinv;
            uint2 agg2; agg2.x = *(unsigned*)&q01; agg2.y = *(unsigned*)&q23;
            *(uint2*)&sA[wave * 8 + r][4 * c16] = agg2;
        }
    }

    // B fragments -> registers AFTER gather (wtr is L2-hot)
    f16x8 bf0[4], bf1[4];
    #pragma unroll
    for (int ks = 0; ks < 4; ++ks) {
        bf0[ks] = *(const f16x8*)&wB[(wc * 32 + m) * 136 + 32 * ks + 8 * kg];
        bf1[ks] = *(const f16x8*)&wB[(wc * 32 + 16 + m) * 136 + 32 * ks + 8 * kg];
    }
    __syncthreads();

    f32x4 acc[2];
    acc[0] = (f32x4){0.f, 0.f, 0.f, 0.f};
    acc[1] = (f32x4){0.f, 0.f, 0.f, 0.f};
    int r0 = (wave >> 1) * 16;
    mfma_regB<4>(&sA[r0][0], 136, m, kg, bf0, bf1, acc);
    int rg = lane >> 4;
    if (!FINAL) {
        #pragma unroll
        for (int nt = 0; nt < 2; ++nt) {
            int col = wc * 32 + nt * 16 + m;
            float bv = bias[col];
            f32x4 a = (nt == 0) ? acc[0] : acc[1];
            #pragma unroll
            for (int i = 0; i < 4; ++i) {
                int row = row0 + r0 + rg * 4 + i;
                hout[(size_t)row * HID_C + col] = __float2half(fmaxf(a[i] + bv, 0.f));
            }
        }
    } else {
        __syncthreads();     // all MFMA1 LDS reads complete
        _Float16* sA72 = &sA[0][0];
        #pragma unroll
        for (int nt = 0; nt < 2; ++nt) {
            int col = wc * 32 + nt * 16 + m;
            float bv = bias[col];
            f32x4 a = (nt == 0) ? acc[0] : acc[1];
            #pragma unroll
            for (int i = 0; i < 4; ++i) {
                int rl = r0 + rg * 4 + i;
                sA72[rl * 72 + col] = (_Float16)fmaxf(a[i] + bv, 0.f);
            }
        }
        f16x8 of0[2], of1[2];
        #pragma unroll
        for (int ks = 0; ks < 2; ++ks) {
            of0[ks] = *(const f16x8*)&wO[(wc * 32 + m) * 72 + 32 * ks + 8 * kg];
            of1[ks] = *(const f16x8*)&wO[(wc * 32 + 16 + m) * 72 + 32 * ks + 8 * kg];
        }
        __syncthreads();
        f32x4 acc2[2];
        acc2[0] = (f32x4){0.f, 0.f, 0.f, 0.f};
        acc2[1] = (f32x4){0.f, 0.f, 0.f, 0.f};
        mfma_regB<2>(&sA72[r0 * 72], 72, m, kg, of0, of1, acc2);
        #pragma unroll
        for (int nt = 0; nt < 2; ++nt) {
            int col = wc * 32 + nt * 16 + m;
            f32x4 a = (nt == 0) ? acc2[0] : acc2[1];
            #pragma unroll
            for (int i = 0; i < 4; ++i) {
                int row = row0 + r0 + rg * 4 + i;
                out[(size_t)row * OUT_C + col] = a[i];
            }
        }
    }
}

extern "C" void kernel_launch(void* const* d_in, const int* in_sizes, int n_in,
                              void* d_out, int out_size, void* d_ws, size_t ws_size,
                              hipStream_t stream) {
    const float* x      = (const float*)d_in[0];
    const int*   ei     = (const int*)  d_in[1];
    const float* W_init = (const float*)d_in[2];
    const float* W_self = (const float*)d_in[3];
    const float* W_agg  = (const float*)d_in[4];
    const float* b      = (const float*)d_in[5];
    const float* W_out  = (const float*)d_in[6];
    float* out = (float*)d_out;

    char* ws = (char*)d_ws;
    const size_t KB = 1 << 10;
    int*      bucket_cursor = (int*)(ws + 0);                 // 1.6 KB
    int2*     rc            = (int2*)(ws + 4 * KB);           // 800 KB
    int*      csr           = (int*)(ws + 1024 * KB);         // 6.4 MB
    _Float16* wtr           = (_Float16*)(ws + 7424 * KB);    // 60 KB
    unsigned* gbuck         = (unsigned*)(ws + 8192 * KB);    // 7.82 MB
    __half*   hA            = (__half*)(ws + 18432 * KB);     // 12.8 MB
    __half*   hB            = (__half*)(ws + 32768 * KB);     // 12.8 MB

    const float4*   wtrI  = (const float4*)(wtr);
    const _Float16* wtrL0 = wtr + 8704;
    const _Float16* wtrL1 = wtr + 17408;
    const _Float16* wtrO  = wtr + 26112;

    (void)hipMemsetAsync(bucket_cursor, 0, NBUCK * sizeof(int), stream);
    k1_bin_tr<<<NB_BINCH + NB_TR, 256, 0, stream>>>(ei, bucket_cursor, gbuck,
                                                    W_init, W_self, W_agg, W_out, wtr);
    k2_build_init<<<NBUCK + N_NODES / ROWS, 256, 0, stream>>>(gbuck, bucket_cursor, csr, rc,
                                                              x, wtrI, hA);
    const int GB = N_NODES / ROWS;   // 3125
    fused_layer<false><<<GB, 256, 0, stream>>>(hA, rc, csr, wtrL0, b + 0 * HID_C, hB,
                                               wtrO, out);
    fused_layer<true><<<GB, 256, 0, stream>>>(hB, rc, csr, wtrL1, b + 1 * HID_C, hA,
                                              wtrO, out);
}